// Round 15
// baseline (258.234 us; speedup 1.0000x reference)
//
#include <hip/hip_runtime.h>

#define NROWS 4096
#define DDIM  128
#define NHEAD 8

typedef __attribute__((ext_vector_type(8))) _Float16 half8;
typedef __attribute__((ext_vector_type(4))) float    floatx4;

// async global->LDS, 16B per lane: LDS dest = wave-uniform base + lane*16.
__device__ __forceinline__ void async_cp16(const _Float16* g, _Float16* l){
  __builtin_amdgcn_global_load_lds(
      (const __attribute__((address_space(1))) void*)g,
      (__attribute__((address_space(3))) void*)l, 16, 0, 0);
}

// fp32 sentinels: 500=ws too small, 1000=in_sizes mismatch, 2000=launch fail.
__global__ void fill_kernel(float* __restrict__ out, float val, int n){
  int i = blockIdx.x * 256 + threadIdx.x;
  if (i < n) out[i] = val;
}

__device__ __forceinline__ half8 f32x8_to_h8(const float* p){
  float4 v0 = *(const float4*)p;
  float4 v1 = *(const float4*)(p + 4);
  half8 r;
  r[0] = (_Float16)v0.x; r[1] = (_Float16)v0.y;
  r[2] = (_Float16)v0.z; r[3] = (_Float16)v0.w;
  r[4] = (_Float16)v1.x; r[5] = (_Float16)v1.y;
  r[6] = (_Float16)v1.z; r[7] = (_Float16)v1.w;
  return r;
}

// ---------------------------------------------------------------------------
// Kernel 1: k = x@Wk[h], v = x@Wv[h]; single-term fp16 MFMA (k/q/v are stored
// fp16 anyway — compute noise ~2.5e-3 logits, within budget). Outputs in MFMA
// fragment order with bank swizzle qX = quad ^ ((l4>>1)&3) baked in.
// grid (32, NHEAD): 2 tiles/block; x frags loaded once, W^T staged once per
// matrix (K phase then V phase through the same 34.8KB LDS buffer).
// ---------------------------------------------------------------------------
__global__ __launch_bounds__(256, 2) void proj_kernel(
    const float* __restrict__ x,
    const float* __restrict__ Wk, const float* __restrict__ Wv,
    _Float16* __restrict__ kfo, _Float16* __restrict__ vfo)
{
  __shared__ alignas(16) _Float16 wt[DDIM][136];   // W^T: wt[d][f]
  const int tid = threadIdx.x, lane = tid & 63, wave = tid >> 6;
  const int l4 = lane & 15, quad = lane >> 4;
  const int h = blockIdx.y;

  // x A-frags for both tiles, full K=128 (fp32 -> fp16 once)
  half8 xf[2][4];
#pragma unroll
  for (int t2 = 0; t2 < 2; t2++) {
    const int tile = blockIdx.x * 2 + t2;
    const float* xr = x + (size_t)(tile * 64 + wave * 16 + l4) * DDIM + quad * 8;
#pragma unroll
    for (int t = 0; t < 4; t++) xf[t2][t] = f32x8_to_h8(xr + t * 32);
  }

  for (int z = 0; z < 2; z++) {
    const float* W = (z == 0 ? Wk : Wv) + h * DDIM * DDIM;
    if (z) __syncthreads();            // phase-A frag reads done before restage
    for (int i = tid; i < DDIM * DDIM; i += 256) {
      const int f = i >> 7, d = i & 127;
      wt[d][f] = (_Float16)W[i];       // coalesced read, transpose in LDS
    }
    __syncthreads();

    floatx4 acc[2][8];
#pragma unroll
    for (int t2 = 0; t2 < 2; t2++)
#pragma unroll
      for (int c = 0; c < 8; c++) acc[t2][c] = (floatx4)0.f;

#pragma unroll
    for (int t = 0; t < 4; t++) {
#pragma unroll
      for (int c = 0; c < 8; c++) {
        half8 b = *(const half8*)&wt[c * 16 + l4][t * 32 + quad * 8];
#pragma unroll
        for (int t2 = 0; t2 < 2; t2++)
          acc[t2][c] = __builtin_amdgcn_mfma_f32_16x16x32_f16(xf[t2][t], b, acc[t2][c], 0, 0, 0);
      }
    }

    const int rb = wave * 16 + quad * 4;
#pragma unroll
    for (int t2 = 0; t2 < 2; t2++) {
      const int tile = blockIdx.x * 2 + t2;
      const size_t tilebase = (size_t)(h * 64 + tile) * 8192;
#pragma unroll
      for (int c = 0; c < 8; c++) {
        const int d = c * 16 + l4;
#pragma unroll
        for (int r = 0; r < 4; r++) {
          const int kl = rb + r;
          const float val = acc[t2][c][r];
          if (z == 0) {
            const int c2 = kl >> 4, l4k = kl & 15;
            const int tt = d >> 5, qd = (d >> 3) & 3, jj = d & 7;
            const int qX = qd ^ ((l4k >> 1) & 3);
            kfo[tilebase + (size_t)((c2 * 4 + tt) * 16 + l4k) * 32 + qX * 8 + jj] =
                (_Float16)val;
          } else {
            const int c2 = d >> 4, l4v = d & 15;
            const int tt = kl >> 5, qd = (kl >> 3) & 3, jj = kl & 7;
            const int qX = qd ^ ((l4v >> 1) & 3);
            vfo[tilebase + (size_t)((c2 * 2 + tt) * 16 + l4v) * 32 + qX * 8 + jj] =
                (_Float16)val;
          }
        }
      }
    }
  }
}

// ---------------------------------------------------------------------------
// Kernel 2: flash attention, 128 q-rows/block, SPLIT-K x2, one barrier/iter.
// grid 512: h=bid&7 (XCD-affine), qt=(bid>>3)&31, s=bid>>8.
// Phase 1: q = x@Wq[h] single-term fp16 (full Wq^T staged once).
// Main loop = R14 (best measured): K double-buffered LDS + async cp,
// V frags global->VGPR, per-wave register softmax, alpha-skip, ones-MFMA l.
// LDS union = 49152 B.
// ---------------------------------------------------------------------------
union FlashLds {
  _Float16 wq[DDIM][136];                            // 34816 B
  float qf[64][132];                                 // 33792 B
  struct { _Float16 k[2][8192], p[4][2][1024]; } kv; // 49152 B
};

__global__ __launch_bounds__(256, 2) void flash_kernel(
    const float* __restrict__ x, const float* __restrict__ Wq,
    const _Float16* __restrict__ kfo, const _Float16* __restrict__ vfo,
    _Float16* __restrict__ op, float* __restrict__ mb, float* __restrict__ lb)
{
  __shared__ alignas(16) FlashLds lds;
  const int tid = threadIdx.x, lane = tid & 63, wave = tid >> 6;
  const int l4 = lane & 15, quad = lane >> 4;
  const int h = blockIdx.x & 7, qt = (blockIdx.x >> 3) & 31, s = blockIdx.x >> 8;
  const int q0 = qt * 128;

  half8 aq[2][4];  // [row-group g][t] fp16 A-frags

  // ---- phase 1: q = x @ Wq[h], single-term fp16 ----
  {
    const float* Wqh = Wq + h * DDIM * DDIM;
    for (int i = tid; i < DDIM * DDIM; i += 256) {
      const int f = i >> 7, d = i & 127;
      lds.wq[d][f] = (_Float16)Wqh[i];
    }
    __syncthreads();

    half8 xf2[2][4];
#pragma unroll
    for (int sp = 0; sp < 2; sp++) {
      const float* xr = x + (size_t)(q0 + sp * 64 + wave * 16 + l4) * DDIM + quad * 8;
#pragma unroll
      for (int t = 0; t < 4; t++) xf2[sp][t] = f32x8_to_h8(xr + t * 32);
    }

    floatx4 qacc[2][8];
#pragma unroll
    for (int sp = 0; sp < 2; sp++)
#pragma unroll
      for (int c = 0; c < 8; c++) qacc[sp][c] = (floatx4)0.f;
#pragma unroll
    for (int t = 0; t < 4; t++) {
#pragma unroll
      for (int c = 0; c < 8; c++) {
        half8 b = *(const half8*)&lds.wq[c * 16 + l4][t * 32 + quad * 8];
#pragma unroll
        for (int sp = 0; sp < 2; sp++)
          qacc[sp][c] = __builtin_amdgcn_mfma_f32_16x16x32_f16(xf2[sp][t], b, qacc[sp][c], 0, 0, 0);
      }
    }
    __syncthreads();  // wq reads done; qf may overwrite

#pragma unroll
    for (int sp = 0; sp < 2; sp++) {
#pragma unroll
      for (int c = 0; c < 8; c++)
#pragma unroll
        for (int r = 0; r < 4; r++)
          lds.qf[wave * 16 + quad * 4 + r][c * 16 + l4] = qacc[sp][c][r];
      __syncthreads();
      if ((wave >> 1) == sp) {
#pragma unroll
        for (int g = 0; g < 2; g++)
#pragma unroll
          for (int t = 0; t < 4; t++)
            aq[g][t] = f32x8_to_h8(&lds.qf[(wave & 1) * 32 + g * 16 + l4][t * 32 + quad * 8]);
      }
      __syncthreads();
    }
  }

  // ---- kt loop: one barrier per iteration (R14 structure) ----
  float m_run[2][4];
#pragma unroll
  for (int g = 0; g < 2; g++)
#pragma unroll
    for (int r = 0; r < 4; r++) m_run[g][r] = -1e30f;
  floatx4 Oacc[2][8], lacc[2];
#pragma unroll
  for (int g = 0; g < 2; g++) {
    lacc[g] = (floatx4)0.f;
#pragma unroll
    for (int c = 0; c < 8; c++) Oacc[g][c] = (floatx4)0.f;
  }

  half8 vones;
#pragma unroll
  for (int j = 0; j < 8; j++) vones[j] = (_Float16)1.f;

  const _Float16* kfo_h = kfo + (size_t)h * 64 * 8192;
  const _Float16* vfo_h = vfo + (size_t)h * 64 * 8192;
  const int lq = (l4 * 4 + (quad ^ ((l4 >> 1) & 3))) * 8;
  const int kt0 = s * 32, kt1 = kt0 + 32;

  {
    const _Float16* ks = kfo_h + (size_t)kt0 * 8192 + wave * 2048 + lane * 8;
    _Float16* kd = &lds.kv.k[0][wave * 2048];
#pragma unroll
    for (int it = 0; it < 4; it++) async_cp16(ks + it * 512, kd + it * 512);
  }

  for (int kt = kt0; kt < kt1; ++kt) {
    const int cur = kt & 1;
    __syncthreads();  // drains K(kt) copies; all waves done with k[cur^1]

    half8 vfrag[8][2];
    {
      const _Float16* vtb = vfo_h + (size_t)kt * 8192;
#pragma unroll
      for (int c = 0; c < 8; c++)
#pragma unroll
        for (int t = 0; t < 2; t++)
          vfrag[c][t] = *(const half8*)(vtb + (c * 2 + t) * 512 + lq);
    }
    if (kt + 1 < kt1) {
      const _Float16* ks = kfo_h + (size_t)(kt + 1) * 8192 + wave * 2048 + lane * 8;
      _Float16* kd = &lds.kv.k[cur ^ 1][wave * 2048];
#pragma unroll
      for (int it = 0; it < 4; it++) async_cp16(ks + it * 512, kd + it * 512);
    }

    floatx4 Sf[2][4];
#pragma unroll
    for (int g = 0; g < 2; g++)
#pragma unroll
      for (int c = 0; c < 4; c++) Sf[g][c] = (floatx4)0.f;
#pragma unroll
    for (int t = 0; t < 4; t++) {
      half8 b[4];
#pragma unroll
      for (int c = 0; c < 4; c++)
        b[c] = *(const half8*)&lds.kv.k[cur][(c * 4 + t) * 512 + lq];
#pragma unroll
      for (int g = 0; g < 2; g++)
#pragma unroll
        for (int c = 0; c < 4; c++)
          Sf[g][c] = __builtin_amdgcn_mfma_f32_16x16x32_f16(aq[g][t], b[c], Sf[g][c], 0, 0, 0);
    }

    float alpha[2][4];
#pragma unroll
    for (int g = 0; g < 2; g++) {
      float mt[4];
#pragma unroll
      for (int r = 0; r < 4; r++)
        mt[r] = fmaxf(fmaxf(Sf[g][0][r], Sf[g][1][r]), fmaxf(Sf[g][2][r], Sf[g][3][r]));
#pragma unroll
      for (int mk = 1; mk <= 8; mk <<= 1)
#pragma unroll
        for (int r = 0; r < 4; r++) mt[r] = fmaxf(mt[r], __shfl_xor(mt[r], mk, 64));
#pragma unroll
      for (int r = 0; r < 4; r++) {
        const float mn = fmaxf(m_run[g][r], mt[r]);
        alpha[g][r] = __expf(m_run[g][r] - mn);
        m_run[g][r] = mn;
      }
#pragma unroll
      for (int r = 0; r < 4; r++)
#pragma unroll
        for (int c = 0; c < 4; c++) Sf[g][c][r] = __expf(Sf[g][c][r] - m_run[g][r]);
    }

#pragma unroll
    for (int g = 0; g < 2; g++)
#pragma unroll
      for (int c = 0; c < 4; c++)
#pragma unroll
        for (int r = 0; r < 4; r++)
          lds.kv.p[wave][g][((c * 2 + (l4 >> 3)) * 16 + quad * 4 + r) * 8 + (l4 & 7)] =
              (_Float16)Sf[g][c][r];

#pragma unroll
    for (int g = 0; g < 2; g++) {
      const bool moved = (alpha[g][0] != 1.f) | (alpha[g][1] != 1.f) |
                         (alpha[g][2] != 1.f) | (alpha[g][3] != 1.f);
      if (__any(moved)) {
#pragma unroll
        for (int c = 0; c < 8; c++) {
          Oacc[g][c][0] *= alpha[g][0]; Oacc[g][c][1] *= alpha[g][1];
          Oacc[g][c][2] *= alpha[g][2]; Oacc[g][c][3] *= alpha[g][3];
        }
        lacc[g][0] *= alpha[g][0]; lacc[g][1] *= alpha[g][1];
        lacc[g][2] *= alpha[g][2]; lacc[g][3] *= alpha[g][3];
      }
    }
#pragma unroll
    for (int t = 0; t < 2; t++) {
      half8 ap[2];
#pragma unroll
      for (int g = 0; g < 2; g++) {
        ap[g] = *(const half8*)&lds.kv.p[wave][g][((t * 4 + quad) * 16 + l4) * 8];
        lacc[g] = __builtin_amdgcn_mfma_f32_16x16x32_f16(ap[g], vones, lacc[g], 0, 0, 0);
      }
#pragma unroll
      for (int c = 0; c < 8; c++)
#pragma unroll
        for (int g = 0; g < 2; g++)
          Oacc[g][c] = __builtin_amdgcn_mfma_f32_16x16x32_f16(ap[g], vfrag[c][t], Oacc[g][c], 0, 0, 0);
    }
  }

  // ---- epilogue: unnormalized partial O (fp16) + per-row (m, l) ----
#pragma unroll
  for (int g = 0; g < 2; g++) {
    const int rbase = wave * 32 + g * 16 + quad * 4;
    const size_t rowbase = (size_t)(s * NHEAD + h) * NROWS + q0 + rbase;
#pragma unroll
    for (int c = 0; c < 8; c++) {
      const int col = c * 16 + l4;
#pragma unroll
      for (int r = 0; r < 4; r++)
        op[(rowbase + r) * DDIM + col] = (_Float16)Oacc[g][c][r];
    }
    if (l4 == 0) {
#pragma unroll
      for (int r = 0; r < 4; r++) {
        mb[rowbase + r] = m_run[g][r];
        lb[rowbase + r] = lacc[g][r];
      }
    }
  }
}

// ---------------------------------------------------------------------------
// Kernel 3: fused merge + MLP. Per 64-row block: per-row split-K/head scales
// -> u-tile built directly from op -> h = x+u (fp16) -> single-term fp16 MFMA
// y = x + relu(h @ Wg^T + bg). grid 64, block 256. LDS = 56320 B.
// ---------------------------------------------------------------------------
__global__ __launch_bounds__(256, 2) void mlp_kernel(
    const float* __restrict__ x,
    const _Float16* __restrict__ op, const float* __restrict__ mb,
    const float* __restrict__ lb, const float* __restrict__ Wm,
    const float* __restrict__ Wg, const float* __restrict__ bg,
    float* __restrict__ out)
{
  __shared__ alignas(16) _Float16 wg_s[DDIM][136];   // 34816 B
  __shared__ alignas(16) _Float16 h_s[64][136];      // 17408 B
  __shared__ float sc_s[64][16];                     //  4096 B
  const int tid = threadIdx.x, lane = tid & 63, wave = tid >> 6;
  const int l4 = lane & 15, quad = lane >> 4;
  const int r0 = blockIdx.x * 64;

  // stage Wg (row-major = B^T directly)
  for (int i = tid; i < DDIM * DDIM; i += 256)
    wg_s[i >> 7][i & 127] = (_Float16)Wg[i];

  // per-row merge scales
  if (tid < 64) {
    const int n = r0 + tid;
#pragma unroll
    for (int hh = 0; hh < NHEAD; hh++) {
      const float m1 = mb[(size_t)hh * NROWS + n];
      const float m2 = mb[(size_t)(NHEAD + hh) * NROWS + n];
      const float l1 = lb[(size_t)hh * NROWS + n];
      const float l2 = lb[(size_t)(NHEAD + hh) * NROWS + n];
      const float m  = fmaxf(m1, m2);
      const float a1 = __expf(m1 - m), a2 = __expf(m2 - m);
      const float invL = Wm[hh] / (l1 * a1 + l2 * a2);
      sc_s[tid][hh] = a1 * invL;
      sc_s[tid][NHEAD + hh] = a2 * invL;
    }
  }
  __syncthreads();

  // h tile: h = x + sum_{s,h} sc * op   (op sh-major matches flash layout)
  for (int it = 0; it < 32; it++) {
    const int e = tid + 256 * it;
    const int d = e & 127, r = e >> 7;
    const int n = r0 + r;
    float acc = x[(size_t)n * DDIM + d];
#pragma unroll
    for (int sh = 0; sh < 16; sh++)
      acc += sc_s[r][sh] * (float)op[((size_t)sh * NROWS + n) * DDIM + d];
    h_s[r][d] = (_Float16)acc;
  }
  __syncthreads();

  floatx4 acc[8];
#pragma unroll
  for (int c = 0; c < 8; c++) acc[c] = (floatx4)0.f;
#pragma unroll
  for (int t = 0; t < 4; t++) {
    half8 a = *(const half8*)&h_s[wave * 16 + l4][t * 32 + quad * 8];
#pragma unroll
    for (int c = 0; c < 8; c++) {
      half8 b = *(const half8*)&wg_s[c * 16 + l4][t * 32 + quad * 8];
      acc[c] = __builtin_amdgcn_mfma_f32_16x16x32_f16(a, b, acc[c], 0, 0, 0);
    }
  }

  const int rbase = wave * 16 + quad * 4;
#pragma unroll
  for (int c = 0; c < 8; c++) {
    const int col = c * 16 + l4;
    const float bgf = bg[col];
#pragma unroll
    for (int r = 0; r < 4; r++) {
      const size_t idx = (size_t)(r0 + rbase + r) * DDIM + col;
      out[idx] = x[idx] + fmaxf(acc[c][r] + bgf, 0.f);
    }
  }
}

extern "C" void kernel_launch(void* const* d_in, const int* in_sizes, int n_in,
                              void* d_out, int out_size, void* d_ws, size_t ws_size,
                              hipStream_t stream) {
  float* out = (float*)d_out;
  const int fill_blocks = (out_size + 255) / 256;

  const bool ok_sizes =
      n_in == 7 &&
      in_sizes[0] == NROWS * DDIM &&
      in_sizes[1] == NHEAD * DDIM * DDIM &&
      in_sizes[2] == NHEAD * DDIM * DDIM &&
      in_sizes[3] == NHEAD * DDIM * DDIM &&
      in_sizes[4] == NHEAD &&
      in_sizes[5] == DDIM * DDIM &&
      in_sizes[6] == DDIM &&
      out_size == NROWS * DDIM;
  if (!ok_sizes) {
    fill_kernel<<<fill_blocks, 256, 0, stream>>>(out, 1000.f, out_size);
    return;
  }

  // ws: kfo 8.4 + vfo 8.4 + op(2) 16.8 + mb/lb 0.5 = 34.1MB
  const size_t HND = (size_t)NHEAD * NROWS * DDIM;
  const size_t need = 2 * HND * 2 + 2 * HND * 2 + 2 * NHEAD * NROWS * 8;
  if (ws_size < need) {
    fill_kernel<<<fill_blocks, 256, 0, stream>>>(out, 500.f, out_size);
    return;
  }

  const float* x  = (const float*)d_in[0];
  const float* Wk = (const float*)d_in[1];
  const float* Wq = (const float*)d_in[2];
  const float* Wv = (const float*)d_in[3];
  const float* Wm = (const float*)d_in[4];
  const float* Wg = (const float*)d_in[5];
  const float* bg = (const float*)d_in[6];

  _Float16*  kfo = (_Float16*)d_ws;
  _Float16*  vfo = kfo + HND;
  _Float16*  op  = vfo + HND;
  float*     mb  = (float*)(op + 2 * HND);
  float*     lb  = mb + 2 * NHEAD * NROWS;

  (void)hipGetLastError();
  proj_kernel<<<dim3(32, NHEAD), 256, 0, stream>>>(x, Wk, Wv, kfo, vfo);
  flash_kernel<<<dim3(512), 256, 0, stream>>>(x, Wq, kfo, vfo, op, mb, lb);
  mlp_kernel<<<dim3(64), 256, 0, stream>>>(x, op, mb, lb, Wm, Wg, bg, out);
  if (hipGetLastError() != hipSuccess) {
    fill_kernel<<<fill_blocks, 256, 0, stream>>>(out, 2000.f, out_size);
  }
}